// Round 18
// baseline (167.056 us; speedup 1.0000x reference)
//
#include <hip/hip_runtime.h>
#include <cstdint>

#define B 64
#define L 512
#define EMB 400
#define KPAD 416
#define H 256
#define NL 3
#define NE 512
#define MAXA 32
#define M_TOT (B * L)

typedef unsigned short u16;
typedef float f32x4 __attribute__((ext_vector_type(4)));
typedef short short8 __attribute__((ext_vector_type(8)));
typedef u16 u16x8 __attribute__((ext_vector_type(8)));

__device__ __forceinline__ float b2f(u16 u) {
  unsigned v = ((unsigned)u) << 16;
  return __builtin_bit_cast(float, v);
}
__device__ __forceinline__ u16 f2b(float f) {
  unsigned u = __builtin_bit_cast(unsigned, f);
  unsigned r = (u + 0x7fffu + ((u >> 16) & 1u)) >> 16;
  return (u16)r;
}

#define GL16(g, l)                                                              \
  __builtin_amdgcn_global_load_lds((const __attribute__((address_space(1))) void*)(g), \
                                   (__attribute__((address_space(3))) void*)(l), 16, 0, 0)

// ---------------------------------------------------------------------------
// k_chain: FUSED Semb-transpose + conv + highway x2. All row-local, so one
// block owns 64 rows end-to-end with GLOBAL-memory handoffs between phases
// (identical traffic to the split version — handoff reads are L2-hot, written
// by this block moments earlier). __syncthreads() between phases = store-drain
// + barrier. LDS union: conv 77KB / HW 72KB -> 77KB, 2 blocks/CU.
// Numerics: byte-identical rounding points to the split r17 version.
// ---------------------------------------------------------------------------
__global__ __launch_bounds__(256, 2) void k_chain(
    const float* __restrict__ Semb, const u16* __restrict__ W1b,
    const u16* __restrict__ HWGb, const u16* __restrict__ HWLb,
    const float* __restrict__ gbias, const float* __restrict__ lbias,
    u16* __restrict__ X1, u16* __restrict__ T1, u16* __restrict__ Xout) {
  __shared__ u16 U[39424];                      // 77 KB union
  // conv-phase aliases
  u16* At = U;                                  // 26624 u16 (52KB)
  u16* Bt = U + 26624;                          // 8192 u16 (16KB)
  u16 (*tmp2)[72] = (u16(*)[72])(U + 34816);    // 4608 u16 (9KB)
  // hw-phase aliases
  u16* Bl0 = U;                                 // 8192
  u16* Bl1 = U + 8192;
  u16* Cl0 = U + 16384;
  u16* Cl1 = U + 24576;
  u16* Al0 = U + 32768;                         // 2048
  u16* Al1 = U + 34816;

  const int t = threadIdx.x;
  const int wid = t >> 6, lane = t & 63;
  const int m0 = blockIdx.x * 64;
  const int b = m0 >> 9, l0 = m0 & 511;
  const int fr = lane & 15, kg = lane >> 4;
  const int r4 = t >> 2, ksg = t & 3;
  const int r0 = kg * 4;
  const int c0 = wid * 64 + fr;

  // ======== phase 0: transpose Semb -> At (early step-0 B prefetch) ========
  {
    const int kc0 = ksg * 8;
#pragma unroll
    for (int c = 0; c < 4; ++c)
      GL16(W1b + (size_t)(c * 64 + r4) * KPAD + kc0, Bt + (size_t)(c * 256 + wid * 64) * 8);
  }
  for (int et = 0; et < 7; ++et) {
    const int e0 = et * 64;
    const int erows = (et < 6) ? 64 : 32;
    {
      const int er = t >> 2, ls = (t & 3) * 16;
      if (er < erows) {
        if (e0 + er < EMB) {
          const float* src = Semb + ((size_t)b * EMB + e0 + er) * L + l0 + ls;
#pragma unroll
          for (int i = 0; i < 4; ++i) {
            const float4 v = *(const float4*)(src + i * 4);
            tmp2[er][ls + i * 4 + 0] = f2b(v.x);
            tmp2[er][ls + i * 4 + 1] = f2b(v.y);
            tmp2[er][ls + i * 4 + 2] = f2b(v.z);
            tmp2[er][ls + i * 4 + 3] = f2b(v.w);
          }
        } else {
#pragma unroll
          for (int i = 0; i < 16; ++i) tmp2[er][ls + i] = 0;
        }
      }
    }
    __syncthreads();
    {
      const int lr = t >> 2, es = (t & 3) * 16;
      if (es < erows) {
        u16x8 v0, v1;
#pragma unroll
        for (int i = 0; i < 8; ++i) v0[i] = tmp2[es + i][lr];
#pragma unroll
        for (int i = 0; i < 8; ++i) v1[i] = tmp2[es + 8 + i][lr];
        const int k = e0 + es;
        u16* dst = At + (((size_t)(k >> 5) * 64 + lr) * 4 + ((k & 31) >> 3)) * 8;
        *(u16x8*)dst = v0;
        *(u16x8*)(dst + 8) = v1;
      }
    }
    __syncthreads();
  }

  // ======== phase 1: conv k-loop (B single-buffered; At resident) ========
  {
    f32x4 acc[4][4] = {};
    for (int kk = 0; kk < (KPAD >> 5); ++kk) {
      if (kk > 0) {
        const int kc = kk * 32 + ksg * 8;
#pragma unroll
        for (int c = 0; c < 4; ++c)
          GL16(W1b + (size_t)(c * 64 + r4) * KPAD + kc, Bt + (size_t)(c * 256 + wid * 64) * 8);
      }
      asm volatile("s_waitcnt vmcnt(0)" ::: "memory");
      __builtin_amdgcn_s_barrier();
      asm volatile("" ::: "memory");
      short8 af[4], bf[4];
#pragma unroll
      for (int i = 0; i < 4; ++i) {
        af[i] = *(const short8*)(At + ((size_t)(kk * 64 + i * 16 + fr) * 4 + kg) * 8);
        bf[i] = *(const short8*)(Bt + ((size_t)(wid * 64 + i * 16 + fr) * 4 + kg) * 8);
      }
#pragma unroll
      for (int mi = 0; mi < 4; ++mi)
#pragma unroll
        for (int ni = 0; ni < 4; ++ni)
          acc[mi][ni] =
              __builtin_amdgcn_mfma_f32_16x16x32_bf16(af[mi], bf[ni], acc[mi][ni], 0, 0, 0);
      __builtin_amdgcn_s_barrier();
      asm volatile("" ::: "memory");
    }
    // conv epilogue -> X1 (global handoff)
#pragma unroll
    for (int ni = 0; ni < 4; ++ni) {
      const int col = c0 + ni * 16;
#pragma unroll
      for (int mi = 0; mi < 4; ++mi)
#pragma unroll
        for (int rr = 0; rr < 4; ++rr)
          X1[(size_t)(m0 + mi * 16 + r0 + rr) * H + col] = f2b(acc[mi][ni][rr]);
    }
  }
  __syncthreads();  // drain x1 stores; free LDS for HW aliases

  // ======== phases 2,3: highway layers (BK=32 dual-buffered dual-B) ========
  for (int layer = 0; layer < 2; ++layer) {
    const u16* Ain = layer ? T1 : X1;
    u16* Oout = layer ? Xout : T1;
    const u16* Gw = HWGb + layer * H * H;
    const u16* Lw = HWLb + layer * H * H;
    f32x4 acc[4][4] = {};
    f32x4 acc2[4][4] = {};

    auto stage = [&](u16* Ab, u16* Bb, u16* Cb, int kk) {
      const int kc = kk * 32 + ksg * 8;
#pragma unroll
      for (int c = 0; c < 4; ++c) {
        GL16(Gw + (size_t)(c * 64 + r4) * H + kc, Bb + (size_t)(c * 256 + wid * 64) * 8);
        GL16(Lw + (size_t)(c * 64 + r4) * H + kc, Cb + (size_t)(c * 256 + wid * 64) * 8);
      }
      GL16(Ain + (size_t)(m0 + r4) * H + kc, Ab + (size_t)(wid * 64) * 8);
    };
    auto compute = [&](const u16* Ab, const u16* Bb, const u16* Cb) {
      short8 af[4], bf[4], cf[4];
#pragma unroll
      for (int i = 0; i < 4; ++i) {
        af[i] = *(const short8*)(Ab + ((size_t)(i * 16 + fr) * 4 + kg) * 8);
        bf[i] = *(const short8*)(Bb + ((size_t)(wid * 64 + i * 16 + fr) * 4 + kg) * 8);
        cf[i] = *(const short8*)(Cb + ((size_t)(wid * 64 + i * 16 + fr) * 4 + kg) * 8);
      }
#pragma unroll
      for (int mi = 0; mi < 4; ++mi)
#pragma unroll
        for (int ni = 0; ni < 4; ++ni) {
          acc[mi][ni] =
              __builtin_amdgcn_mfma_f32_16x16x32_bf16(af[mi], bf[ni], acc[mi][ni], 0, 0, 0);
          acc2[mi][ni] =
              __builtin_amdgcn_mfma_f32_16x16x32_bf16(af[mi], cf[ni], acc2[mi][ni], 0, 0, 0);
        }
    };

    stage(Al0, Bl0, Cl0, 0);
    for (int kk = 0; kk < 8; ++kk) {
      u16* Ac = (kk & 1) ? Al1 : Al0;
      u16* Bc = (kk & 1) ? Bl1 : Bl0;
      u16* Cc = (kk & 1) ? Cl1 : Cl0;
      u16* An = (kk & 1) ? Al0 : Al1;
      u16* Bn = (kk & 1) ? Bl0 : Bl1;
      u16* Cn = (kk & 1) ? Cl0 : Cl1;
      if (kk + 1 < 8) {
        stage(An, Bn, Cn, kk + 1);
        asm volatile("s_waitcnt vmcnt(9)" ::: "memory");
      } else {
        asm volatile("s_waitcnt vmcnt(0)" ::: "memory");
      }
      __builtin_amdgcn_s_barrier();
      asm volatile("" ::: "memory");
      compute(Ac, Bc, Cc);
      __builtin_amdgcn_s_barrier();
      asm volatile("" ::: "memory");
    }
#pragma unroll
    for (int ni = 0; ni < 4; ++ni) {
      const int col = c0 + ni * 16;
      const float b1 = gbias[layer * H + col];
      const float b2 = lbias[layer * H + col];
#pragma unroll
      for (int mi = 0; mi < 4; ++mi)
#pragma unroll
        for (int rr = 0; rr < 4; ++rr) {
          const int row = m0 + mi * 16 + r0 + rr;
          const float g = 1.f / (1.f + __expf(-(acc[mi][ni][rr] + b1)));
          const float nn = acc2[mi][ni][rr] + b2;
          const float x = b2f(Ain[(size_t)row * H + col]);  // L2-hot (own block)
          Oout[(size_t)row * H + col] = f2b(g * nn + (1.f - g) * x);
        }
    }
    __syncthreads();  // drain stores before next layer reads them / reuses LDS
  }
}

// ---------------------------------------------------------------------------
// GCN GEMM, BK=64 counted-vmcnt dbuf (r15-proven). LAST=true: yv only.
// ---------------------------------------------------------------------------
template <bool LAST>
__global__ __launch_bounds__(256, 2) void gemm64gcn(
    const u16* __restrict__ A, const u16* __restrict__ Bw,
    const float* __restrict__ bias1, const float* __restrict__ rden,
    const float* __restrict__ cw, float* __restrict__ yv, u16* __restrict__ Out) {
  __shared__ u16 Bl0[2 * 256 * 32];   // 32 KB
  __shared__ u16 Bl1[2 * 256 * 32];
  __shared__ u16 Al0[2 * 64 * 32];    // 8 KB
  __shared__ u16 Al1[2 * 64 * 32];

  const int t = threadIdx.x;
  const int wid = t >> 6, lane = t & 63;
  const int m0 = blockIdx.x * 64;
  const int fr = lane & 15, kg = lane >> 4;
  const int r4 = t >> 2, ksg = t & 3;

  f32x4 acc[4][4] = {};

  auto stage = [&](u16* Ab, u16* Bb, int kk) {
#pragma unroll
    for (int h = 0; h < 2; ++h) {
      const int kc = kk * 64 + h * 32 + ksg * 8;
#pragma unroll
      for (int c = 0; c < 4; ++c)
        GL16(Bw + (size_t)(c * 64 + r4) * H + kc,
             Bb + (size_t)h * 8192 + (size_t)(c * 256 + wid * 64) * 8);
      GL16(A + (size_t)(m0 + r4) * H + kc,
           Ab + (size_t)h * 2048 + (size_t)(wid * 64) * 8);
    }
  };
  auto compute = [&](const u16* Ab, const u16* Bb) {
#pragma unroll
    for (int h = 0; h < 2; ++h) {
      short8 af[4], bf[4];
#pragma unroll
      for (int i = 0; i < 4; ++i) {
        af[i] = *(const short8*)(Ab + (size_t)h * 2048 + ((size_t)(i * 16 + fr) * 4 + kg) * 8);
        bf[i] = *(const short8*)(Bb + (size_t)h * 8192 +
                                 ((size_t)(wid * 64 + i * 16 + fr) * 4 + kg) * 8);
      }
#pragma unroll
      for (int mi = 0; mi < 4; ++mi)
#pragma unroll
        for (int ni = 0; ni < 4; ++ni)
          acc[mi][ni] =
              __builtin_amdgcn_mfma_f32_16x16x32_bf16(af[mi], bf[ni], acc[mi][ni], 0, 0, 0);
    }
  };

  const int nk = H >> 6;  // 4
  stage(Al0, Bl0, 0);
  for (int kk = 0; kk < nk; ++kk) {
    u16* Ac = (kk & 1) ? Al1 : Al0;
    u16* Bc = (kk & 1) ? Bl1 : Bl0;
    u16* An = (kk & 1) ? Al0 : Al1;
    u16* Bn = (kk & 1) ? Bl0 : Bl1;
    if (kk + 1 < nk) {
      stage(An, Bn, kk + 1);
      asm volatile("s_waitcnt vmcnt(10)" ::: "memory");
    } else {
      asm volatile("s_waitcnt vmcnt(0)" ::: "memory");
    }
    __builtin_amdgcn_s_barrier();
    asm volatile("" ::: "memory");
    compute(Ac, Bc);
    __builtin_amdgcn_s_barrier();
    asm volatile("" ::: "memory");
  }

  const int r0 = kg * 4;
  const int c0 = wid * 64 + fr;
  float ypart[16];
#pragma unroll
  for (int q = 0; q < 16; ++q) ypart[q] = 0.f;
#pragma unroll
  for (int ni = 0; ni < 4; ++ni) {
    const int col = c0 + ni * 16;
    const float b1 = 2.f * bias1[col];
    const float cwv = cw[col];
#pragma unroll
    for (int mi = 0; mi < 4; ++mi)
#pragma unroll
      for (int rr = 0; rr < 4; ++rr) {
        const int row = m0 + mi * 16 + r0 + rr;
        const float s = (acc[mi][ni][rr] + b1) * rden[row];
        const float rl = s > 0.f ? s : 0.f;
        ypart[mi * 4 + rr] += rl * cwv;
        if constexpr (!LAST) Out[(size_t)row * H + col] = f2b(rl);
      }
  }
#pragma unroll
  for (int q = 0; q < 16; ++q) {
    float p = ypart[q];
    p += __shfl_xor(p, 1);
    p += __shfl_xor(p, 2);
    p += __shfl_xor(p, 4);
    p += __shfl_xor(p, 8);
    if (fr == 0) atomicAdd(&yv[m0 + (q >> 2) * 16 + r0 + (q & 3)], p);
  }
}

// T[m,:] = h[m,:] + sum_{s in adj row} h[s,:]  (8 tok/block, u16x8, high TLP)
__global__ __launch_bounds__(256) void k_gather(const unsigned* __restrict__ bm,
                                                const u16* __restrict__ h,
                                                u16* __restrict__ T) {
  const int t = threadIdx.x;
  const int tok = blockIdx.x * 8 + (t >> 5);
  const int b = tok >> 9;
  const int c = (t & 31) * 8;
  const uint4* wp4 = (const uint4*)(bm + (size_t)tok * 16);
  const uint4 w0 = wp4[0], w1 = wp4[1], w2 = wp4[2], w3 = wp4[3];
  const unsigned wa[16] = {w0.x, w0.y, w0.z, w0.w, w1.x, w1.y, w1.z, w1.w,
                           w2.x, w2.y, w2.z, w2.w, w3.x, w3.y, w3.z, w3.w};
  float acc[8];
  {
    const u16x8 v = *(const u16x8*)(h + (size_t)tok * H + c);
#pragma unroll
    for (int i = 0; i < 8; ++i) acc[i] = b2f(v[i]);
  }
#pragma unroll
  for (int wi = 0; wi < 16; ++wi) {
    unsigned bits = wa[wi];
    while (bits) {
      const int bit = __ffs(bits) - 1;
      bits &= bits - 1;
      const int s = wi * 32 + bit;
      const u16x8 u = *(const u16x8*)(h + (size_t)(b * L + s) * H + c);
#pragma unroll
      for (int i = 0; i < 8; ++i) acc[i] += b2f(u[i]);
    }
  }
  u16x8 o;
#pragma unroll
  for (int i = 0; i < 8; ++i) o[i] = f2b(acc[i]);
  *(u16x8*)(T + (size_t)tok * H + c) = o;
}

// ---------------------------------------------------------------------------
// k_prep2: blocks [0,B): per-batch LDS-bitmap edges + rden + yv zero;
//          blocks [B,...): weight conversions.
// ---------------------------------------------------------------------------
__global__ __launch_bounds__(256) void k_prep2(const int* __restrict__ edges,
                                               unsigned* __restrict__ bm,
                                               float* __restrict__ rden,
                                               float* __restrict__ yv,
                                               const float* __restrict__ W1,
                                               const float* __restrict__ gW,
                                               const float* __restrict__ lW,
                                               const float* __restrict__ gcnW,
                                               u16* __restrict__ W1b, u16* __restrict__ HWGb,
                                               u16* __restrict__ HWLb, u16* __restrict__ GCNb) {
  const int t = threadIdx.x;
  if (blockIdx.x < B) {
    __shared__ unsigned lbm[512 * 16];   // 32 KB
    const int b = blockIdx.x;
#pragma unroll
    for (int i = 0; i < 32; ++i) lbm[i * 256 + t] = 0;
    __syncthreads();
#pragma unroll
    for (int e = 0; e < 2; ++e) {
      const int idx = t * 2 + e;
      const int u = edges[((size_t)b * NE + idx) * 2 + 0];
      const int v = edges[((size_t)b * NE + idx) * 2 + 1];
      atomicOr(&lbm[u * 16 + (v >> 5)], 1u << (v & 31));
      atomicOr(&lbm[v * 16 + (u >> 5)], 1u << (u & 31));
    }
    __syncthreads();
    uint4* gbm = (uint4*)(bm + (size_t)b * 512 * 16);
    const uint4* lb4 = (const uint4*)lbm;
#pragma unroll
    for (int i = 0; i < 8; ++i) gbm[i * 256 + t] = lb4[i * 256 + t];
#pragma unroll
    for (int r = 0; r < 2; ++r) {
      const int row = t * 2 + r;
      int c = 0;
#pragma unroll
      for (int w = 0; w < 16; ++w) c += __popc(lbm[row * 16 + w]);
      rden[(size_t)b * 512 + row] = 1.f / (1.f + (float)c);
    }
#pragma unroll
    for (int i = 0; i < 2; ++i) yv[(size_t)b * 512 + i * 256 + t] = 0.f;
    return;
  }
  int i = (blockIdx.x - B) * 256 + t;
  if (i < 256 * KPAD) {
    const int o = i / KPAD, k = i - o * KPAD;
    W1b[i] = (k < EMB) ? f2b(W1[o * EMB + k]) : (u16)0;
    return;
  }
  i -= 256 * KPAD;
  if (i < 2 * H * H) { HWGb[i] = f2b(gW[i]); return; }
  i -= 2 * H * H;
  if (i < 2 * H * H) { HWLb[i] = f2b(lW[i]); return; }
  i -= 2 * H * H;
  if (i < NL * H * H) GCNb[i] = f2b(gcnW[i]);
}

// logits + maskA
__global__ __launch_bounds__(256) void k_logits(const float* __restrict__ yv,
                                                const float* __restrict__ cb,
                                                const float* __restrict__ lw,
                                                const float* __restrict__ lb,
                                                const int* __restrict__ wids,
                                                const int* __restrict__ y1,
                                                const int* __restrict__ y2,
                                                float* __restrict__ out) {
  if (blockIdx.x == B * 2) {
#pragma unroll
    for (int j = 0; j < 8; ++j) {
      const int idx = j * 256 + threadIdx.x;
      const int b = idx >> 5, q = idx & 31;
      out[B * L + idx] = (y1[b] + q <= y2[b]) ? 1.0f : 0.0f;
    }
    return;
  }
  const int b = blockIdx.x >> 1;
  const int m = ((blockIdx.x & 1) << 8) + threadIdx.x;
  __shared__ float ys[512];
  const float cb0 = cb[0];
  ys[threadIdx.x] = fmaxf(yv[(size_t)b * L + threadIdx.x] + cb0, 0.f);
  ys[threadIdx.x + 256] = fmaxf(yv[(size_t)b * L + 256 + threadIdx.x] + cb0, 0.f);
  __syncthreads();
  float acc = lb[m];
  const float4* wr = (const float4*)(lw + (size_t)m * L);
#pragma unroll 4
  for (int l4 = 0; l4 < 128; ++l4) {
    const float4 w4 = wr[l4];
    acc += ys[l4 * 4] * w4.x + ys[l4 * 4 + 1] * w4.y + ys[l4 * 4 + 2] * w4.z +
           ys[l4 * 4 + 3] * w4.w;
  }
  out[(size_t)b * L + m] = (wids[(size_t)b * L + m] != 0) ? acc : -1.0e30f;
}

extern "C" void kernel_launch(void* const* d_in, const int* in_sizes, int n_in,
                              void* d_out, int out_size, void* d_ws, size_t ws_size,
                              hipStream_t stream) {
  (void)in_sizes; (void)n_in; (void)out_size; (void)ws_size;
  const float* Semb      = (const float*)d_in[0];
  const int*   wids      = (const int*)d_in[1];
  const int*   y1        = (const int*)d_in[2];
  const int*   y2        = (const int*)d_in[3];
  const int*   edges     = (const int*)d_in[4];
  const float* W1        = (const float*)d_in[5];
  const float* hw_lin_W  = (const float*)d_in[6];
  const float* hw_lin_b  = (const float*)d_in[7];
  const float* hw_gate_W = (const float*)d_in[8];
  const float* hw_gate_b = (const float*)d_in[9];
  const float* gcn_W     = (const float*)d_in[10];
  const float* gcn_b     = (const float*)d_in[11];
  const float* conv_W    = (const float*)d_in[12];
  const float* conv_b    = (const float*)d_in[13];
  const float* lin_W     = (const float*)d_in[14];
  const float* lin_b     = (const float*)d_in[15];
  float* out = (float*)d_out;

  char* ws = (char*)d_ws;
  const size_t SZX = (size_t)M_TOT * H * 2;      // 16,777,216
  u16* P0b  = (u16*)(ws);
  u16* P1b  = (u16*)(ws + SZX);
  u16* O0   = (u16*)(ws + 2 * SZX);
  u16* O1   = (u16*)(ws + 3 * SZX);
  char* wp  = ws + 4 * SZX;
  u16* W1b  = (u16*)(wp);                         // 212,992
  u16* HWGb = (u16*)(wp + 212992);                // 262,144
  u16* HWLb = (u16*)(wp + 212992 + 262144);       // 262,144
  u16* GCNb = (u16*)(wp + 212992 + 2 * 262144);   // 393,216
  char* sp  = wp + 212992 + 2 * 262144 + 393216;
  unsigned* bm   = (unsigned*)(sp);               // 2 MB
  float*    yv   = (float*)(sp + 2097152);        // 128 KB
  float*    rden = (float*)(sp + 2097152 + 131072);

  // adjacency + rden + yv zero + weight conversions, one dispatch
  const int ncvt = 256 * KPAD + 4 * H * H + NL * H * H;
  k_prep2<<<dim3(B + (ncvt + 255) / 256), 256, 0, stream>>>(
      edges, bm, rden, yv, W1, hw_gate_W, hw_lin_W, gcn_W, W1b, HWGb, HWLb, GCNb);

  // fused transpose + conv + highway x2 (row-local chain; global handoffs
  // x1->O0, hw1->P1b, hw2->P0b)
  k_chain<<<dim3(M_TOT / 64), 256, 0, stream>>>(Semb, W1b, HWGb, HWLb,
                                                hw_gate_b, hw_lin_b, O0, P1b, P0b);

  // GCN layers: high-TLP gather, then BK=64 GEMM w/ fused yv accumulation
  k_gather<<<dim3(M_TOT / 8), 256, 0, stream>>>(bm, P0b, P1b);
  gemm64gcn<false><<<dim3(M_TOT / 64), 256, 0, stream>>>(P1b, GCNb, gcn_b, rden,
                                                         conv_W, yv, O0);
  k_gather<<<dim3(M_TOT / 8), 256, 0, stream>>>(bm, O0, P0b);
  gemm64gcn<false><<<dim3(M_TOT / 64), 256, 0, stream>>>(P0b, GCNb + H * H, gcn_b + H, rden,
                                                         conv_W + H, yv, O1);
  k_gather<<<dim3(M_TOT / 8), 256, 0, stream>>>(bm, O1, P1b);
  gemm64gcn<true><<<dim3(M_TOT / 64), 256, 0, stream>>>(P1b, GCNb + 2 * H * H, gcn_b + 2 * H,
                                                        rden, conv_W + 2 * H, yv, nullptr);

  // head (+ maskA in the extra block)
  k_logits<<<dim3(B * 2 + 1), 256, 0, stream>>>(yv, conv_b, lin_W, lin_b, wids, y1, y2, out);
}

// Round 19
// 166.081 us; speedup vs baseline: 1.0059x; 1.0059x over previous
//
#include <hip/hip_runtime.h>
#include <cstdint>

#define B 64
#define L 512
#define EMB 400
#define KPAD 416
#define H 256
#define NL 3
#define NE 512
#define MAXA 32
#define M_TOT (B * L)

typedef unsigned short u16;
typedef float f32x4 __attribute__((ext_vector_type(4)));
typedef short short8 __attribute__((ext_vector_type(8)));
typedef u16 u16x8 __attribute__((ext_vector_type(8)));

__device__ __forceinline__ float b2f(u16 u) {
  unsigned v = ((unsigned)u) << 16;
  return __builtin_bit_cast(float, v);
}
__device__ __forceinline__ u16 f2b(float f) {
  unsigned u = __builtin_bit_cast(unsigned, f);
  unsigned r = (u + 0x7fffu + ((u >> 16) & 1u)) >> 16;
  return (u16)r;
}

#define GL16(g, l)                                                              \
  __builtin_amdgcn_global_load_lds((const __attribute__((address_space(1))) void*)(g), \
                                   (__attribute__((address_space(3))) void*)(l), 16, 0, 0)

// ---------------------------------------------------------------------------
// FUSED Semb-transpose + conv GEMM (r13/r15-proven). One block = 64 tokens.
// tmp stride 69 (was 72): 144B stride put scalar-u16 transpose stores on 16
// multiples-of-4 banks (4-way conflict, since r2); 138B spreads ~2-way (free).
// ---------------------------------------------------------------------------
__global__ __launch_bounds__(256, 2) void k_convT(const float* __restrict__ Semb,
                                                  const u16* __restrict__ W1b,
                                                  u16* __restrict__ Out) {
  __shared__ u16 smem[64 * KPAD + 256 * 32];   // At (52KB) + Bt (16KB)
  u16* At = smem;
  u16* Bt = smem + 64 * KPAD;
  u16 (*tmp)[69] = (u16(*)[69])Bt;             // 64x69 u16 = 8832B < 16KB

  const int t = threadIdx.x;
  const int wid = t >> 6, lane = t & 63;
  const int m0 = blockIdx.x * 64;
  const int b = m0 >> 9, l0 = m0 & 511;
  const int fr = lane & 15, kg = lane >> 4;
  const int r4 = t >> 2, ksg = t & 3;

  // ---- phase 1: transpose into At ----
  for (int et = 0; et < 7; ++et) {
    const int e0 = et * 64;
    const int erows = (et < 6) ? 64 : 32;
    {
      const int er = t >> 2, ls = (t & 3) * 16;
      if (er < erows) {
        if (e0 + er < EMB) {
          const float* src = Semb + ((size_t)b * EMB + e0 + er) * L + l0 + ls;
#pragma unroll
          for (int i = 0; i < 4; ++i) {
            const float4 v = *(const float4*)(src + i * 4);
            tmp[er][ls + i * 4 + 0] = f2b(v.x);
            tmp[er][ls + i * 4 + 1] = f2b(v.y);
            tmp[er][ls + i * 4 + 2] = f2b(v.z);
            tmp[er][ls + i * 4 + 3] = f2b(v.w);
          }
        } else {
#pragma unroll
          for (int i = 0; i < 16; ++i) tmp[er][ls + i] = 0;
        }
      }
    }
    __syncthreads();
    {
      const int lr = t >> 2, es = (t & 3) * 16;
      if (es < erows) {
        u16x8 v0, v1;
#pragma unroll
        for (int i = 0; i < 8; ++i) v0[i] = tmp[es + i][lr];
#pragma unroll
        for (int i = 0; i < 8; ++i) v1[i] = tmp[es + 8 + i][lr];
        const int k = e0 + es;
        u16* dst = At + (((size_t)(k >> 5) * 64 + lr) * 4 + ((k & 31) >> 3)) * 8;
        *(u16x8*)dst = v0;
        *(u16x8*)(dst + 8) = v1;
      }
    }
    __syncthreads();
  }

  // ---- phase 2: k-loop (B single-buffered; At resident) ----
  f32x4 acc[4][4] = {};
  for (int kk = 0; kk < (KPAD >> 5); ++kk) {
    const int kc = kk * 32 + ksg * 8;
#pragma unroll
    for (int c = 0; c < 4; ++c)
      GL16(W1b + (size_t)(c * 64 + r4) * KPAD + kc, Bt + (size_t)(c * 256 + wid * 64) * 8);
    asm volatile("s_waitcnt vmcnt(0)" ::: "memory");
    __builtin_amdgcn_s_barrier();
    asm volatile("" ::: "memory");
    short8 af[4], bf[4];
#pragma unroll
    for (int i = 0; i < 4; ++i) {
      af[i] = *(const short8*)(At + ((size_t)(kk * 64 + i * 16 + fr) * 4 + kg) * 8);
      bf[i] = *(const short8*)(Bt + ((size_t)(wid * 64 + i * 16 + fr) * 4 + kg) * 8);
    }
#pragma unroll
    for (int mi = 0; mi < 4; ++mi)
#pragma unroll
      for (int ni = 0; ni < 4; ++ni)
        acc[mi][ni] = __builtin_amdgcn_mfma_f32_16x16x32_bf16(af[mi], bf[ni], acc[mi][ni], 0, 0, 0);
    __builtin_amdgcn_s_barrier();
    asm volatile("" ::: "memory");
  }

  const int r0 = kg * 4;
  const int c0 = wid * 64 + fr;
#pragma unroll
  for (int ni = 0; ni < 4; ++ni) {
    const int col = c0 + ni * 16;
#pragma unroll
    for (int mi = 0; mi < 4; ++mi)
#pragma unroll
      for (int rr = 0; rr < 4; ++rr)
        Out[(size_t)(m0 + mi * 16 + r0 + rr) * H + col] = f2b(acc[mi][ni][rr]);
  }
}

// ---------------------------------------------------------------------------
// Highway GEMM (dual-B, BK=32, counted-vmcnt double-buffered; r15-proven).
// ---------------------------------------------------------------------------
__global__ __launch_bounds__(256, 2) void gemm64hw(
    const u16* __restrict__ A, const u16* __restrict__ Bw, const u16* __restrict__ B2w,
    const float* __restrict__ bias1, const float* __restrict__ bias2,
    u16* __restrict__ Out) {
  __shared__ u16 Bl0[256 * 32];
  __shared__ u16 Bl1[256 * 32];
  __shared__ u16 Cl0[256 * 32];
  __shared__ u16 Cl1[256 * 32];
  __shared__ u16 Al0[64 * 32];
  __shared__ u16 Al1[64 * 32];

  const int t = threadIdx.x;
  const int wid = t >> 6, lane = t & 63;
  const int m0 = blockIdx.x * 64;
  const int fr = lane & 15, kg = lane >> 4;
  const int r4 = t >> 2, ksg = t & 3;

  f32x4 acc[4][4] = {};
  f32x4 acc2[4][4] = {};

  auto stage = [&](u16* Ab, u16* Bb, u16* Cb, int kk) {
    const int kc = kk * 32 + ksg * 8;
#pragma unroll
    for (int c = 0; c < 4; ++c) {
      GL16(Bw + (size_t)(c * 64 + r4) * H + kc, Bb + (size_t)(c * 256 + wid * 64) * 8);
      GL16(B2w + (size_t)(c * 64 + r4) * H + kc, Cb + (size_t)(c * 256 + wid * 64) * 8);
    }
    GL16(A + (size_t)(m0 + r4) * H + kc, Ab + (size_t)(wid * 64) * 8);
  };
  auto compute = [&](const u16* Ab, const u16* Bb, const u16* Cb) {
    short8 af[4], bf[4], cf[4];
#pragma unroll
    for (int i = 0; i < 4; ++i) {
      af[i] = *(const short8*)(Ab + ((size_t)(i * 16 + fr) * 4 + kg) * 8);
      bf[i] = *(const short8*)(Bb + ((size_t)(wid * 64 + i * 16 + fr) * 4 + kg) * 8);
      cf[i] = *(const short8*)(Cb + ((size_t)(wid * 64 + i * 16 + fr) * 4 + kg) * 8);
    }
#pragma unroll
    for (int mi = 0; mi < 4; ++mi)
#pragma unroll
      for (int ni = 0; ni < 4; ++ni) {
        acc[mi][ni] = __builtin_amdgcn_mfma_f32_16x16x32_bf16(af[mi], bf[ni], acc[mi][ni], 0, 0, 0);
        acc2[mi][ni] = __builtin_amdgcn_mfma_f32_16x16x32_bf16(af[mi], cf[ni], acc2[mi][ni], 0, 0, 0);
      }
  };

  const int nk = H >> 5;  // 8
  stage(Al0, Bl0, Cl0, 0);
  for (int kk = 0; kk < nk; ++kk) {
    u16* Ac = (kk & 1) ? Al1 : Al0;
    u16* Bc = (kk & 1) ? Bl1 : Bl0;
    u16* Cc = (kk & 1) ? Cl1 : Cl0;
    u16* An = (kk & 1) ? Al0 : Al1;
    u16* Bn = (kk & 1) ? Bl0 : Bl1;
    u16* Cn = (kk & 1) ? Cl0 : Cl1;
    if (kk + 1 < nk) {
      stage(An, Bn, Cn, kk + 1);
      asm volatile("s_waitcnt vmcnt(9)" ::: "memory");
    } else {
      asm volatile("s_waitcnt vmcnt(0)" ::: "memory");
    }
    __builtin_amdgcn_s_barrier();
    asm volatile("" ::: "memory");
    compute(Ac, Bc, Cc);
    __builtin_amdgcn_s_barrier();
    asm volatile("" ::: "memory");
  }

  const int r0 = kg * 4;
  const int c0 = wid * 64 + fr;
#pragma unroll
  for (int ni = 0; ni < 4; ++ni) {
    const int col = c0 + ni * 16;
    const float b1 = bias1[col], b2 = bias2[col];
#pragma unroll
    for (int mi = 0; mi < 4; ++mi)
#pragma unroll
      for (int rr = 0; rr < 4; ++rr) {
        const int row = m0 + mi * 16 + r0 + rr;
        const float g = 1.f / (1.f + __expf(-(acc[mi][ni][rr] + b1)));
        const float nn = acc2[mi][ni][rr] + b2;
        const float x = b2f(A[(size_t)row * H + col]);  // residual, L2-hot
        Out[(size_t)row * H + col] = f2b(g * nn + (1.f - g) * x);
      }
  }
}

// ---------------------------------------------------------------------------
// GCN GEMM, BK=64 counted-vmcnt dbuf (r15-proven). LAST=true: yv only.
// ---------------------------------------------------------------------------
template <bool LAST>
__global__ __launch_bounds__(256, 2) void gemm64gcn(
    const u16* __restrict__ A, const u16* __restrict__ Bw,
    const float* __restrict__ bias1, const float* __restrict__ rden,
    const float* __restrict__ cw, float* __restrict__ yv, u16* __restrict__ Out) {
  __shared__ u16 Bl0[2 * 256 * 32];   // 32 KB
  __shared__ u16 Bl1[2 * 256 * 32];
  __shared__ u16 Al0[2 * 64 * 32];    // 8 KB
  __shared__ u16 Al1[2 * 64 * 32];

  const int t = threadIdx.x;
  const int wid = t >> 6, lane = t & 63;
  const int m0 = blockIdx.x * 64;
  const int fr = lane & 15, kg = lane >> 4;
  const int r4 = t >> 2, ksg = t & 3;

  f32x4 acc[4][4] = {};

  auto stage = [&](u16* Ab, u16* Bb, int kk) {
#pragma unroll
    for (int h = 0; h < 2; ++h) {
      const int kc = kk * 64 + h * 32 + ksg * 8;
#pragma unroll
      for (int c = 0; c < 4; ++c)
        GL16(Bw + (size_t)(c * 64 + r4) * H + kc,
             Bb + (size_t)h * 8192 + (size_t)(c * 256 + wid * 64) * 8);
      GL16(A + (size_t)(m0 + r4) * H + kc,
           Ab + (size_t)h * 2048 + (size_t)(wid * 64) * 8);
    }
  };
  auto compute = [&](const u16* Ab, const u16* Bb) {
#pragma unroll
    for (int h = 0; h < 2; ++h) {
      short8 af[4], bf[4];
#pragma unroll
      for (int i = 0; i < 4; ++i) {
        af[i] = *(const short8*)(Ab + (size_t)h * 2048 + ((size_t)(i * 16 + fr) * 4 + kg) * 8);
        bf[i] = *(const short8*)(Bb + (size_t)h * 8192 +
                                 ((size_t)(wid * 64 + i * 16 + fr) * 4 + kg) * 8);
      }
#pragma unroll
      for (int mi = 0; mi < 4; ++mi)
#pragma unroll
        for (int ni = 0; ni < 4; ++ni)
          acc[mi][ni] =
              __builtin_amdgcn_mfma_f32_16x16x32_bf16(af[mi], bf[ni], acc[mi][ni], 0, 0, 0);
    }
  };

  const int nk = H >> 6;  // 4
  stage(Al0, Bl0, 0);
  for (int kk = 0; kk < nk; ++kk) {
    u16* Ac = (kk & 1) ? Al1 : Al0;
    u16* Bc = (kk & 1) ? Bl1 : Bl0;
    u16* An = (kk & 1) ? Al0 : Al1;
    u16* Bn = (kk & 1) ? Bl0 : Bl1;
    if (kk + 1 < nk) {
      stage(An, Bn, kk + 1);
      asm volatile("s_waitcnt vmcnt(10)" ::: "memory");
    } else {
      asm volatile("s_waitcnt vmcnt(0)" ::: "memory");
    }
    __builtin_amdgcn_s_barrier();
    asm volatile("" ::: "memory");
    compute(Ac, Bc);
    __builtin_amdgcn_s_barrier();
    asm volatile("" ::: "memory");
  }

  const int r0 = kg * 4;
  const int c0 = wid * 64 + fr;
  float ypart[16];
#pragma unroll
  for (int q = 0; q < 16; ++q) ypart[q] = 0.f;
#pragma unroll
  for (int ni = 0; ni < 4; ++ni) {
    const int col = c0 + ni * 16;
    const float b1 = 2.f * bias1[col];
    const float cwv = cw[col];
#pragma unroll
    for (int mi = 0; mi < 4; ++mi)
#pragma unroll
      for (int rr = 0; rr < 4; ++rr) {
        const int row = m0 + mi * 16 + r0 + rr;
        const float s = (acc[mi][ni][rr] + b1) * rden[row];
        const float rl = s > 0.f ? s : 0.f;
        ypart[mi * 4 + rr] += rl * cwv;
        if constexpr (!LAST) Out[(size_t)row * H + col] = f2b(rl);
      }
  }
#pragma unroll
  for (int q = 0; q < 16; ++q) {
    float p = ypart[q];
    p += __shfl_xor(p, 1);
    p += __shfl_xor(p, 2);
    p += __shfl_xor(p, 4);
    p += __shfl_xor(p, 8);
    if (fr == 0) atomicAdd(&yv[m0 + (q >> 2) * 16 + r0 + (q & 3)], p);
  }
}

// T[m,:] = h[m,:] + sum_{s in adj row} h[s,:]  (8 tok/block, u16x8, high TLP)
__global__ __launch_bounds__(256) void k_gather(const unsigned* __restrict__ bm,
                                                const u16* __restrict__ h,
                                                u16* __restrict__ T) {
  const int t = threadIdx.x;
  const int tok = blockIdx.x * 8 + (t >> 5);
  const int b = tok >> 9;
  const int c = (t & 31) * 8;
  const uint4* wp4 = (const uint4*)(bm + (size_t)tok * 16);
  const uint4 w0 = wp4[0], w1 = wp4[1], w2 = wp4[2], w3 = wp4[3];
  const unsigned wa[16] = {w0.x, w0.y, w0.z, w0.w, w1.x, w1.y, w1.z, w1.w,
                           w2.x, w2.y, w2.z, w2.w, w3.x, w3.y, w3.z, w3.w};
  float acc[8];
  {
    const u16x8 v = *(const u16x8*)(h + (size_t)tok * H + c);
#pragma unroll
    for (int i = 0; i < 8; ++i) acc[i] = b2f(v[i]);
  }
#pragma unroll
  for (int wi = 0; wi < 16; ++wi) {
    unsigned bits = wa[wi];
    while (bits) {
      const int bit = __ffs(bits) - 1;
      bits &= bits - 1;
      const int s = wi * 32 + bit;
      const u16x8 u = *(const u16x8*)(h + (size_t)(b * L + s) * H + c);
#pragma unroll
      for (int i = 0; i < 8; ++i) acc[i] += b2f(u[i]);
    }
  }
  u16x8 o;
#pragma unroll
  for (int i = 0; i < 8; ++i) o[i] = f2b(acc[i]);
  *(u16x8*)(T + (size_t)tok * H + c) = o;
}

// ---------------------------------------------------------------------------
// k_prep2: blocks [0,B): per-batch LDS-bitmap edges + rden + yv zero;
//          blocks [B,...): weight conversions.
// ---------------------------------------------------------------------------
__global__ __launch_bounds__(256) void k_prep2(const int* __restrict__ edges,
                                               unsigned* __restrict__ bm,
                                               float* __restrict__ rden,
                                               float* __restrict__ yv,
                                               const float* __restrict__ W1,
                                               const float* __restrict__ gW,
                                               const float* __restrict__ lW,
                                               const float* __restrict__ gcnW,
                                               u16* __restrict__ W1b, u16* __restrict__ HWGb,
                                               u16* __restrict__ HWLb, u16* __restrict__ GCNb) {
  const int t = threadIdx.x;
  if (blockIdx.x < B) {
    __shared__ unsigned lbm[512 * 16];   // 32 KB
    const int b = blockIdx.x;
#pragma unroll
    for (int i = 0; i < 32; ++i) lbm[i * 256 + t] = 0;
    __syncthreads();
#pragma unroll
    for (int e = 0; e < 2; ++e) {
      const int idx = t * 2 + e;
      const int u = edges[((size_t)b * NE + idx) * 2 + 0];
      const int v = edges[((size_t)b * NE + idx) * 2 + 1];
      atomicOr(&lbm[u * 16 + (v >> 5)], 1u << (v & 31));
      atomicOr(&lbm[v * 16 + (u >> 5)], 1u << (u & 31));
    }
    __syncthreads();
    uint4* gbm = (uint4*)(bm + (size_t)b * 512 * 16);
    const uint4* lb4 = (const uint4*)lbm;
#pragma unroll
    for (int i = 0; i < 8; ++i) gbm[i * 256 + t] = lb4[i * 256 + t];
#pragma unroll
    for (int r = 0; r < 2; ++r) {
      const int row = t * 2 + r;
      int c = 0;
#pragma unroll
      for (int w = 0; w < 16; ++w) c += __popc(lbm[row * 16 + w]);
      rden[(size_t)b * 512 + row] = 1.f / (1.f + (float)c);
    }
#pragma unroll
    for (int i = 0; i < 2; ++i) yv[(size_t)b * 512 + i * 256 + t] = 0.f;
    return;
  }
  int i = (blockIdx.x - B) * 256 + t;
  if (i < 256 * KPAD) {
    const int o = i / KPAD, k = i - o * KPAD;
    W1b[i] = (k < EMB) ? f2b(W1[o * EMB + k]) : (u16)0;
    return;
  }
  i -= 256 * KPAD;
  if (i < 2 * H * H) { HWGb[i] = f2b(gW[i]); return; }
  i -= 2 * H * H;
  if (i < 2 * H * H) { HWLb[i] = f2b(lW[i]); return; }
  i -= 2 * H * H;
  if (i < NL * H * H) GCNb[i] = f2b(gcnW[i]);
}

// logits + maskA
__global__ __launch_bounds__(256) void k_logits(const float* __restrict__ yv,
                                                const float* __restrict__ cb,
                                                const float* __restrict__ lw,
                                                const float* __restrict__ lb,
                                                const int* __restrict__ wids,
                                                const int* __restrict__ y1,
                                                const int* __restrict__ y2,
                                                float* __restrict__ out) {
  if (blockIdx.x == B * 2) {
#pragma unroll
    for (int j = 0; j < 8; ++j) {
      const int idx = j * 256 + threadIdx.x;
      const int b = idx >> 5, q = idx & 31;
      out[B * L + idx] = (y1[b] + q <= y2[b]) ? 1.0f : 0.0f;
    }
    return;
  }
  const int b = blockIdx.x >> 1;
  const int m = ((blockIdx.x & 1) << 8) + threadIdx.x;
  __shared__ float ys[512];
  const float cb0 = cb[0];
  ys[threadIdx.x] = fmaxf(yv[(size_t)b * L + threadIdx.x] + cb0, 0.f);
  ys[threadIdx.x + 256] = fmaxf(yv[(size_t)b * L + 256 + threadIdx.x] + cb0, 0.f);
  __syncthreads();
  float acc = lb[m];
  const float4* wr = (const float4*)(lw + (size_t)m * L);
#pragma unroll 4
  for (int l4 = 0; l4 < 128; ++l4) {
    const float4 w4 = wr[l4];
    acc += ys[l4 * 4] * w4.x + ys[l4 * 4 + 1] * w4.y + ys[l4 * 4 + 2] * w4.z +
           ys[l4 * 4 + 3] * w4.w;
  }
  out[(size_t)b * L + m] = (wids[(size_t)b * L + m] != 0) ? acc : -1.0e30f;
}

extern "C" void kernel_launch(void* const* d_in, const int* in_sizes, int n_in,
                              void* d_out, int out_size, void* d_ws, size_t ws_size,
                              hipStream_t stream) {
  (void)in_sizes; (void)n_in; (void)out_size; (void)ws_size;
  const float* Semb      = (const float*)d_in[0];
  const int*   wids      = (const int*)d_in[1];
  const int*   y1        = (const int*)d_in[2];
  const int*   y2        = (const int*)d_in[3];
  const int*   edges     = (const int*)d_in[4];
  const float* W1        = (const float*)d_in[5];
  const float* hw_lin_W  = (const float*)d_in[6];
  const float* hw_lin_b  = (const float*)d_in[7];
  const float* hw_gate_W = (const float*)d_in[8];
  const float* hw_gate_b = (const float*)d_in[9];
  const float* gcn_W     = (const float*)d_in[10];
  const float* gcn_b     = (const float*)d_in[11];
  const float* conv_W    = (const float*)d_in[12];
  const float* conv_b    = (const float*)d_in[13];
  const float* lin_W     = (const float*)d_in[14];
  const float* lin_b     = (const float*)d_in[15];
  float* out = (float*)d_out;

  char* ws = (char*)d_ws;
  const size_t SZX = (size_t)M_TOT * H * 2;      // 16,777,216
  u16* P0b  = (u16*)(ws);
  u16* P1b  = (u16*)(ws + SZX);
  u16* O0   = (u16*)(ws + 2 * SZX);
  u16* O1   = (u16*)(ws + 3 * SZX);
  char* wp  = ws + 4 * SZX;
  u16* W1b  = (u16*)(wp);                         // 212,992
  u16* HWGb = (u16*)(wp + 212992);                // 262,144
  u16* HWLb = (u16*)(wp + 212992 + 262144);       // 262,144
  u16* GCNb = (u16*)(wp + 212992 + 2 * 262144);   // 393,216
  char* sp  = wp + 212992 + 2 * 262144 + 393216;
  unsigned* bm   = (unsigned*)(sp);               // 2 MB
  float*    yv   = (float*)(sp + 2097152);        // 128 KB
  float*    rden = (float*)(sp + 2097152 + 131072);

  // adjacency + rden + yv zero + weight conversions, one dispatch
  const int ncvt = 256 * KPAD + 4 * H * H + NL * H * H;
  k_prep2<<<dim3(B + (ncvt + 255) / 256), 256, 0, stream>>>(
      edges, bm, rden, yv, W1, hw_gate_W, hw_lin_W, gcn_W, W1b, HWGb, HWLb, GCNb);

  // fused transpose + conv 1x1
  k_convT<<<dim3(M_TOT / 64), 256, 0, stream>>>(Semb, W1b, P0b);

  // highway x2 (BK=32 dual-buffered counted-vmcnt; residual re-read from A)
  gemm64hw<<<dim3(M_TOT / 64), 256, 0, stream>>>(P0b, HWGb, HWLb, hw_gate_b, hw_lin_b, P1b);
  gemm64hw<<<dim3(M_TOT / 64), 256, 0, stream>>>(P1b, HWGb + H * H, HWLb + H * H,
                                                 hw_gate_b + H, hw_lin_b + H, P0b);

  // GCN layers: high-TLP gather, then BK=64 GEMM w/ fused yv accumulation
  k_gather<<<dim3(M_TOT / 8), 256, 0, stream>>>(bm, P0b, P1b);
  gemm64gcn<false><<<dim3(M_TOT / 64), 256, 0, stream>>>(P1b, GCNb, gcn_b, rden,
                                                         conv_W, yv, O0);
  k_gather<<<dim3(M_TOT / 8), 256, 0, stream>>>(bm, O0, P0b);
  gemm64gcn<false><<<dim3(M_TOT / 64), 256, 0, stream>>>(P0b, GCNb + H * H, gcn_b + H, rden,
                                                         conv_W + H, yv, O1);
  k_gather<<<dim3(M_TOT / 8), 256, 0, stream>>>(bm, O1, P1b);
  gemm64gcn<true><<<dim3(M_TOT / 64), 256, 0, stream>>>(P1b, GCNb + 2 * H * H, gcn_b + 2 * H,
                                                        rden, conv_W + 2 * H, yv, nullptr);

  // head (+ maskA in the extra block)
  k_logits<<<dim3(B * 2 + 1), 256, 0, stream>>>(yv, conv_b, lin_W, lin_b, wids, y1, y2, out);
}